// Round 8
// baseline (512.588 us; speedup 1.0000x reference)
//
#include <hip/hip_runtime.h>
#include <hip/hip_bf16.h>
#include <cstdint>
#include <cstddef>

// SelfAttention fused block, MI355X gfx950.
// Round 7: occupancy round.
//  - attn: 4-way kv parity split inside a 256-thr block; 1024 blocks
//    (bh x P), 4 blocks/CU = 16 waves/CU (was 2 blocks/CU). 2-round LDS
//    merge (2 x [64][66] f32 buffers = 34KB -> 4 blocks still resident).
//    XCD decode: f&7 = XCD, 4 heads/XCD; P heavy/light interleaved.
//  - out-proj GEMM: 128x64 tile (template BN) -> grid 512 = 2 blocks/CU
//    (was 256 = 1/CU, 1 wave/SIMD).
//  - prep (x cvt + 2 weight transposes) fused into one launch.
//  - QKV epilogue: v^T scatter now ushort4 (4 consecutive s per thread).
//  - QKV GEMM keeps round-6 BK=64 conflict-free swizzle (T2 null at 2ph but
//    free; schedule tuning abandoned per regime-gate).

using bf16 = __hip_bfloat16;
typedef __attribute__((ext_vector_type(8))) short short8;
typedef __attribute__((ext_vector_type(4))) float f32x4;
typedef __attribute__((ext_vector_type(16))) float f32x16;
typedef __attribute__((ext_vector_type(4))) unsigned int u32x4;

__device__ __forceinline__ unsigned short f2b(float f) {
    bf16 h = __float2bfloat16(f);
    return *reinterpret_cast<unsigned short*>(&h);
}

__device__ __forceinline__ void async16(const void* g, void* l) {
    __builtin_amdgcn_global_load_lds(
        (const __attribute__((address_space(1))) void*)g,
        (__attribute__((address_space(3))) void*)l, 16, 0, 0);
}

// ---------------- K1: fused prep: x fp32->bf16, Wqkv^T, Wo^T -----------------
__global__ __launch_bounds__(256) void prep_kernel(
    const float* __restrict__ x, bf16* __restrict__ x_bf,
    const float* __restrict__ Wqkv, bf16* __restrict__ wqkv_t,
    const float* __restrict__ Wo, bf16* __restrict__ wo_t) {
    const int bid = blockIdx.x;
    const int tid = threadIdx.x;
    if (bid < 4096) {  // cvt: 1M float4
        const int i = bid * 256 + tid;
        const float4 v = reinterpret_cast<const float4*>(x)[i];
        ushort4 o;
        o.x = f2b(v.x); o.y = f2b(v.y); o.z = f2b(v.z); o.w = f2b(v.w);
        reinterpret_cast<ushort4*>(x_bf)[i] = o;
        return;
    }
    // transpose_cvt part
    __shared__ float tile[32][33];
    const float* in;
    bf16* out;
    int K, N, n0, k0;
    if (bid < 4096 + 3072) {
        const int blk = bid - 4096;
        in = Wqkv; out = wqkv_t; K = 1024; N = 3072;
        n0 = (blk % 96) * 32; k0 = (blk / 96) * 32;
    } else {
        const int blk = bid - 7168;
        in = Wo; out = wo_t; K = 1024; N = 1024;
        n0 = (blk % 32) * 32; k0 = (blk / 32) * 32;
    }
    const int tx = tid & 31, ty = tid >> 5;  // (32,8)
    #pragma unroll
    for (int i = 0; i < 32; i += 8)
        tile[ty + i][tx] = in[(size_t)(k0 + ty + i) * N + n0 + tx];
    __syncthreads();
    #pragma unroll
    for (int i = 0; i < 32; i += 8)
        out[(size_t)(n0 + ty + i) * K + k0 + tx] = __float2bfloat16(tile[tx][ty + i]);
}

// ------- K3/K5: 128xBN BK=64 swizzled-LDS bf16 MFMA GEMM, B^T input ----------
// EPI==0: C fp32 = A@B^T + bias.  EPI==1: scatter qkv (bias added, bf16).
template <int EPI, int BN>
__global__ __launch_bounds__(256) void gemm_bt64(
    const bf16* __restrict__ A,   // [M][K] bf16
    const bf16* __restrict__ Bt,  // [N][K] bf16
    const float* __restrict__ bias,  // [N] fp32
    float* __restrict__ Cf,          // EPI==0: [M][N] fp32
    bf16* __restrict__ qd, bf16* __restrict__ kd, bf16* __restrict__ vtd,
    int M, int N, int K) {
    constexpr int NFR = BN / 32;  // B frags per wave (wave n-span = BN/2)
    // LDS tile: elem(row, k) at row*64 + ((k>>3)^(row&7))*8 + (k&7)
    __shared__ bf16 As[128 * 64];
    __shared__ bf16 Bs[BN * 64];
    const int t = threadIdx.x;
    const int lane = t & 63;
    const int lr = lane & 15, lg = lane >> 4;
    const int wave = t >> 6;
    const int wr = wave >> 1, wc = wave & 1;  // 2x2 waves
    const int m0 = blockIdx.x * 128, n0 = blockIdx.y * BN;

    // staging: inst j covers LDS bytes j*4096 + t*16 -> row j*32 + (t>>3),
    // lds-chunk t&7; source chunk = (t&7) ^ (row&7)  (involution)
    const int sRow = t >> 3;
    const int sChunk = (t & 7) ^ (sRow & 7);
    const bf16* aSrc = A + (size_t)(m0 + sRow) * K + sChunk * 8;
    const bf16* bSrc = Bt + (size_t)(n0 + sRow) * K + sChunk * 8;
    const size_t rowStep32 = (size_t)32 * K;

    f32x4 acc[4][NFR] = {};

    for (int k0 = 0; k0 < K; k0 += 64) {
        __syncthreads();  // prev reads done
        #pragma unroll
        for (int j = 0; j < 4; ++j)
            async16(aSrc + j * rowStep32 + k0, &As[j * 2048 + t * 8]);
        #pragma unroll
        for (int j = 0; j < BN / 32; ++j)
            async16(bSrc + j * rowStep32 + k0, &Bs[j * 2048 + t * 8]);
        __syncthreads();  // tiles visible
        #pragma unroll
        for (int kh = 0; kh < 2; ++kh) {
            short8 af[4], bfr[NFR];
            #pragma unroll
            for (int i = 0; i < 4; ++i) {
                const int ar = wr * 64 + i * 16 + lr;
                af[i] = *reinterpret_cast<const short8*>(
                    &As[ar * 64 + ((kh * 4 + lg) ^ (ar & 7)) * 8]);
            }
            #pragma unroll
            for (int i = 0; i < NFR; ++i) {
                const int br = wc * (BN / 2) + i * 16 + lr;
                bfr[i] = *reinterpret_cast<const short8*>(
                    &Bs[br * 64 + ((kh * 4 + lg) ^ (br & 7)) * 8]);
            }
            #pragma unroll
            for (int mi = 0; mi < 4; ++mi)
                #pragma unroll
                for (int ni = 0; ni < NFR; ++ni)
                    acc[mi][ni] = __builtin_amdgcn_mfma_f32_16x16x32_bf16(
                        af[mi], bfr[ni], acc[mi][ni], 0, 0, 0);
        }
    }

    #pragma unroll
    for (int mi = 0; mi < 4; ++mi) {
        #pragma unroll
        for (int ni = 0; ni < NFR; ++ni) {
            const int rowb = m0 + wr * 64 + mi * 16 + lg * 4;
            const int col = n0 + wc * (BN / 2) + ni * 16 + lr;
            if constexpr (EPI == 0) {
                #pragma unroll
                for (int r = 0; r < 4; ++r)
                    Cf[(size_t)(rowb + r) * N + col] = acc[mi][ni][r] + bias[col];
            } else {
                const float bs = bias[col];
                const int part = col >> 10;      // 0=q 1=k 2=v
                const int within = col & 1023;
                const int h = within >> 6, d = within & 63;
                const int b = rowb >> 11, s0 = rowb & 2047;
                const int bh = b * 16 + h;
                if (part == 2) {  // v^T: 4 consecutive s -> ushort4
                    ushort4 pk;
                    pk.x = f2b(acc[mi][ni][0] + bs);
                    pk.y = f2b(acc[mi][ni][1] + bs);
                    pk.z = f2b(acc[mi][ni][2] + bs);
                    pk.w = f2b(acc[mi][ni][3] + bs);
                    *reinterpret_cast<ushort4*>(
                        &vtd[((size_t)bh * 64 + d) * 2048 + s0]) = pk;
                } else {
                    bf16* dst = (part == 0) ? qd : kd;
                    #pragma unroll
                    for (int r = 0; r < 4; ++r)
                        dst[((size_t)bh * 2048 + s0 + r) * 64 + d] =
                            __float2bfloat16(acc[mi][ni][r] + bs);
                }
            }
        }
    }
}

// ---------------- K4: causal flash attention, 4-way kv split -----------------
// grid 1024 (1-D): f&7 = XCD residue r; m = f>>3; bh = r + 8*(m>>5);
// j = m&31 -> P = interleaved heavy/light (bijective). Block = one q-pair
// P (q-tiles 2P, 2P+1 = 64 rows), 4 waves; wave s takes kv tiles t===s mod 4,
// t <= 2P+1. Classification: t<2P dual; t==2P A-diag+B-full; t==2P+1 B-diag.
// Partials merge by ADDITION (no-max softmax linear): 2-round LDS merge.
__global__ __launch_bounds__(256, 4) void attn_kernel(const bf16* __restrict__ q,
                                                      const bf16* __restrict__ k,
                                                      const bf16* __restrict__ vt,
                                                      bf16* __restrict__ o) {
    const int S = 2048;
    const int f = blockIdx.x;
    const int r8 = f & 7, m = f >> 3;
    const int bh = r8 + 8 * (m >> 5);
    const int j = m & 31;
    const int P = (j & 1) ? (j >> 1) : (31 - (j >> 1));
    const int b = bh >> 4, h = bh & 15;
    const int w = threadIdx.x >> 6;  // kv parity 0..3
    const int lane = threadIdx.x & 63;
    const int ln = lane & 31;
    const int hi = lane >> 5;
    const int qbaseA = P * 64;
    const int qbaseB = P * 64 + 32;

    const bf16* qp = q + (size_t)bh * S * 64;
    const bf16* kp = k + (size_t)bh * S * 64;
    const bf16* vp = vt + (size_t)bh * 64 * S;

    short8 qfA[4], qfB[4];
    #pragma unroll
    for (int i = 0; i < 4; ++i) {
        qfA[i] = *reinterpret_cast<const short8*>(
            &qp[(size_t)(qbaseA + ln) * 64 + i * 16 + hi * 8]);
        qfB[i] = *reinterpret_cast<const short8*>(
            &qp[(size_t)(qbaseB + ln) * 64 + i * 16 + hi * 8]);
    }

    f32x16 oA0 = {}, oA1 = {}, oB0 = {}, oB1 = {};
    f32x4 lsvA = {0.f, 0.f, 0.f, 0.f}, lsvB = {0.f, 0.f, 0.f, 0.f};

    short8 kA[4], kB[4], vA[4], vB[4];

    auto kload = [&](short8 (&kf)[4], int tile) {
        const bf16* base = &kp[(size_t)(tile * 32 + ln) * 64 + hi * 8];
        #pragma unroll
        for (int i = 0; i < 4; ++i)
            kf[i] = *reinterpret_cast<const short8*>(base + i * 16);
    };
    auto vload = [&](short8 (&vf)[4], int tile) {
        #pragma unroll
        for (int dblk = 0; dblk < 2; ++dblk)
            #pragma unroll
            for (int half = 0; half < 2; ++half)
                vf[dblk * 2 + half] = *reinterpret_cast<const short8*>(
                    &vp[(size_t)(dblk * 32 + ln) * S + tile * 32 + half * 16 +
                        hi * 8]);
    };

    auto body = [&](const short8 (&kf)[4], const short8 (&vf)[4],
                    const short8 (&qf)[4], f32x16& o0, f32x16& o1, f32x4& lsv,
                    bool diag) {
        f32x16 z0 = {}, z1 = {};
        z0 = __builtin_amdgcn_mfma_f32_32x32x16_bf16(kf[0], qf[0], z0, 0, 0, 0);
        z0 = __builtin_amdgcn_mfma_f32_32x32x16_bf16(kf[1], qf[1], z0, 0, 0, 0);
        z1 = __builtin_amdgcn_mfma_f32_32x32x16_bf16(kf[2], qf[2], z1, 0, 0, 0);
        z1 = __builtin_amdgcn_mfma_f32_32x32x16_bf16(kf[3], qf[3], z1, 0, 0, 0);
        const f32x16 z = z0 + z1;
        f32x16 pv;
        #pragma unroll
        for (int rr = 0; rr < 16; ++rr) {
            const int kreg = (rr & 3) + 8 * (rr >> 2) + 4 * hi;
            float e = __expf(z[rr] * 0.125f);
            if (diag && (kreg > ln)) e = 0.f;
            pv[rr] = e;
            lsv[rr & 3] += e;
        }
        unsigned a0, a1, b0, b1, c0, c1, d0, d1;
        asm("v_cvt_pk_bf16_f32 %0, %1, %2" : "=v"(a0) : "v"(pv[0]), "v"(pv[1]));
        asm("v_cvt_pk_bf16_f32 %0, %1, %2" : "=v"(a1) : "v"(pv[2]), "v"(pv[3]));
        asm("v_cvt_pk_bf16_f32 %0, %1, %2" : "=v"(b0) : "v"(pv[4]), "v"(pv[5]));
        asm("v_cvt_pk_bf16_f32 %0, %1, %2" : "=v"(b1) : "v"(pv[6]), "v"(pv[7]));
        asm("v_cvt_pk_bf16_f32 %0, %1, %2" : "=v"(c0) : "v"(pv[8]), "v"(pv[9]));
        asm("v_cvt_pk_bf16_f32 %0, %1, %2" : "=v"(c1) : "v"(pv[10]), "v"(pv[11]));
        asm("v_cvt_pk_bf16_f32 %0, %1, %2" : "=v"(d0) : "v"(pv[12]), "v"(pv[13]));
        asm("v_cvt_pk_bf16_f32 %0, %1, %2" : "=v"(d1) : "v"(pv[14]), "v"(pv[15]));
        asm("v_permlane32_swap_b32 %0, %1" : "+v"(a0), "+v"(b0));
        asm("v_permlane32_swap_b32 %0, %1" : "+v"(a1), "+v"(b1));
        asm("v_permlane32_swap_b32 %0, %1" : "+v"(c0), "+v"(d0));
        asm("v_permlane32_swap_b32 %0, %1" : "+v"(c1), "+v"(d1));
        u32x4 t0, t1;
        t0[0] = a0; t0[1] = a1; t0[2] = b0; t0[3] = b1;   // P[q][kv 0..15]
        t1[0] = c0; t1[1] = c1; t1[2] = d0; t1[3] = d1;   // P[q][kv 16..31]
        const short8 pa0 = __builtin_bit_cast(short8, t0);
        const short8 pa1 = __builtin_bit_cast(short8, t1);
        o0 = __builtin_amdgcn_mfma_f32_32x32x16_bf16(pa0, vf[0], o0, 0, 0, 0);
        o0 = __builtin_amdgcn_mfma_f32_32x32x16_bf16(pa1, vf[1], o0, 0, 0, 0);
        o1 = __builtin_amdgcn_mfma_f32_32x32x16_bf16(pa0, vf[2], o1, 0, 0, 0);
        o1 = __builtin_amdgcn_mfma_f32_32x32x16_bf16(pa1, vf[3], o1, 0, 0, 0);
    };

    // ---- this wave's kv tiles: t = w + 4*i <= 2P+1 ----
    const int tmax = 2 * P + 1;
    const int n = (tmax >= w) ? ((tmax - w) >> 2) + 1 : 0;
    if (n > 0) {
        kload(kA, w);
        vload(vA, w);
        for (int i = 0; i + 1 < n; ++i) {  // all non-last tiles are t < 2P
            const int tn = w + 4 * (i + 1);
            kload(kB, tn);
            vload(vB, tn);
            body(kA, vA, qfA, oA0, oA1, lsvA, false);
            body(kA, vA, qfB, oB0, oB1, lsvB, false);
            #pragma unroll
            for (int c = 0; c < 4; ++c) { kA[c] = kB[c]; vA[c] = vB[c]; }
        }
        const int tLast = w + 4 * (n - 1);
        if (tLast == 2 * P) {          // A diagonal, B full
            body(kA, vA, qfA, oA0, oA1, lsvA, true);
            body(kA, vA, qfB, oB0, oB1, lsvB, false);
        } else if (tLast == tmax) {    // B diagonal only (A fully masked)
            body(kA, vA, qfB, oB0, oB1, lsvB, true);
        } else {                       // plain dual
            body(kA, vA, qfA, oA0, oA1, lsvA, false);
            body(kA, vA, qfB, oB0, oB1, lsvB, false);
        }
    }

    float lsA = (lsvA[0] + lsvA[1]) + (lsvA[2] + lsvA[3]);
    float lsB = (lsvB[0] + lsvB[1]) + (lsvB[2] + lsvB[3]);

    // ---- 2-round merge: (w2,w3)->(w0,w1), then w1->w0 ----
    __shared__ float red[2][64][66];
    __shared__ float redl[2][64][2];
    auto writeBuf = [&](int bi) {
        float* dst = red[bi][lane];
        #pragma unroll
        for (int rr = 0; rr < 16; ++rr) {
            dst[rr] = oA0[rr];
            dst[16 + rr] = oA1[rr];
            dst[32 + rr] = oB0[rr];
            dst[48 + rr] = oB1[rr];
        }
        redl[bi][lane][0] = lsA;
        redl[bi][lane][1] = lsB;
    };
    auto addBuf = [&](int bi) {
        const float* src = red[bi][lane];
        #pragma unroll
        for (int rr = 0; rr < 16; ++rr) {
            oA0[rr] += src[rr];
            oA1[rr] += src[16 + rr];
            oB0[rr] += src[32 + rr];
            oB1[rr] += src[48 + rr];
        }
        lsA += redl[bi][lane][0];
        lsB += redl[bi][lane][1];
    };
    if (w == 2) writeBuf(0);
    if (w == 3) writeBuf(1);
    __syncthreads();
    if (w == 0) addBuf(0);
    if (w == 1) addBuf(1);
    __syncthreads();
    if (w == 1) writeBuf(0);
    __syncthreads();
    if (w != 0) return;
    addBuf(0);

    // ---- finalize: sum lane halves, normalize, store both q-tiles ----
    lsA += __shfl_xor(lsA, 32, 64);
    lsB += __shfl_xor(lsB, 32, 64);
    const float myInvA = 1.0f / lsA;
    const float myInvB = 1.0f / lsB;
    #pragma unroll
    for (int rr = 0; rr < 16; ++rr) {
        const int qrow = (rr & 3) + 8 * (rr >> 2) + 4 * hi;
        const float invA = __shfl(myInvA, qrow, 64);
        const float invB = __shfl(myInvB, qrow, 64);
        const size_t rowA = ((size_t)b * S + qbaseA + qrow) * 1024 + h * 64;
        const size_t rowB = ((size_t)b * S + qbaseB + qrow) * 1024 + h * 64;
        o[rowA + ln] = __float2bfloat16(oA0[rr] * invA);
        o[rowA + 32 + ln] = __float2bfloat16(oA1[rr] * invA);
        o[rowB + ln] = __float2bfloat16(oB0[rr] * invB);
        o[rowB + 32 + ln] = __float2bfloat16(oB1[rr] * invB);
    }
}

// -----------------------------------------------------------------------------
extern "C" void kernel_launch(void* const* d_in, const int* in_sizes, int n_in,
                              void* d_out, int out_size, void* d_ws, size_t ws_size,
                              hipStream_t stream) {
    const float* x = (const float*)d_in[0];     // [2,2048,1024]
    const float* Wqkv = (const float*)d_in[1];  // [1024,3072]
    const float* bqkv = (const float*)d_in[2];  // [3072]
    const float* Wo = (const float*)d_in[3];    // [1024,1024]
    const float* bo = (const float*)d_in[4];    // [1024]
    float* out = (float*)d_out;                 // [2,2048,1024] fp32
    char* ws = (char*)d_ws;

    // workspace layout (bytes), total 40 MB
    bf16* x_bf = (bf16*)(ws);                  //  8388608  [4096][1024]
    bf16* wqkv_t = (bf16*)(ws + 8388608);      //  6291456  [3072][1024]
    bf16* wo_t = (bf16*)(ws + 14680064);       //  2097152  [1024][1024]
    bf16* qb = (bf16*)(ws + 16777216);         //  8388608  [2,16,2048,64]
    bf16* kb = (bf16*)(ws + 25165824);         //  8388608  [2,16,2048,64]
    bf16* vtb = (bf16*)(ws + 33554432);        //  8388608  [2,16,64,2048]
    bf16* attn_o = x_bf;                       // alias: x_bf dead after gemm1

    prep_kernel<<<8192, 256, 0, stream>>>(x, x_bf, Wqkv, wqkv_t, Wo, wo_t);
    gemm_bt64<1, 128><<<dim3(32, 24), 256, 0, stream>>>(
        x_bf, wqkv_t, bqkv, nullptr, qb, kb, vtb, 4096, 3072, 1024);
    attn_kernel<<<1024, 256, 0, stream>>>(qb, kb, vtb, attn_o);
    gemm_bt64<0, 64><<<dim3(32, 16), 256, 0, stream>>>(
        attn_o, wo_t, bo, out, nullptr, nullptr, nullptr, 4096, 1024, 1024);
}

// Round 9
// 114.482 us; speedup vs baseline: 4.4775x; 4.4775x over previous
//
#include <hip/hip_runtime.h>
#include <hip/hip_bf16.h>
#include <cstdint>
#include <cstddef>

// SelfAttention fused block, MI355X gfx950.
// Round 8: RECOVERY. Round 7's attn (256,4) launch bound capped VGPR at 128
// for a ~230-VGPR structure -> full spill (WRITE_SIZE 741MB, 460us).
//  - attn: revert to round-6 kernel (dual-q, 2-way kv parity split, (256,2)).
//  - QKV: revert to round-5 128x128 BK=32 linear-LDS structure (measured
//    fastest: 48.5us vs 56us for the BK=64 swizzled variant, whose 32KB LDS
//    cut occupancy 23->15% -- at 2-phase, wave overlap beats conflict-free).
//    Keep round-7 ushort4 v^T epilogue.
//  - out-proj: BN=64 template -> grid 512 = 2 blocks/CU.
//  - prep fusion kept (x cvt + both weight transposes, one launch).

using bf16 = __hip_bfloat16;
typedef __attribute__((ext_vector_type(8))) short short8;
typedef __attribute__((ext_vector_type(4))) float f32x4;
typedef __attribute__((ext_vector_type(16))) float f32x16;
typedef __attribute__((ext_vector_type(4))) unsigned int u32x4;

__device__ __forceinline__ unsigned short f2b(float f) {
    bf16 h = __float2bfloat16(f);
    return *reinterpret_cast<unsigned short*>(&h);
}

__device__ __forceinline__ void async16(const void* g, void* l) {
    __builtin_amdgcn_global_load_lds(
        (const __attribute__((address_space(1))) void*)g,
        (__attribute__((address_space(3))) void*)l, 16, 0, 0);
}

// ---------------- K1: fused prep: x fp32->bf16, Wqkv^T, Wo^T -----------------
__global__ __launch_bounds__(256) void prep_kernel(
    const float* __restrict__ x, bf16* __restrict__ x_bf,
    const float* __restrict__ Wqkv, bf16* __restrict__ wqkv_t,
    const float* __restrict__ Wo, bf16* __restrict__ wo_t) {
    const int bid = blockIdx.x;
    const int tid = threadIdx.x;
    if (bid < 4096) {  // cvt: 1M float4
        const int i = bid * 256 + tid;
        const float4 v = reinterpret_cast<const float4*>(x)[i];
        ushort4 o;
        o.x = f2b(v.x); o.y = f2b(v.y); o.z = f2b(v.z); o.w = f2b(v.w);
        reinterpret_cast<ushort4*>(x_bf)[i] = o;
        return;
    }
    __shared__ float tile[32][33];
    const float* in;
    bf16* out;
    int K, N, n0, k0;
    if (bid < 4096 + 3072) {
        const int blk = bid - 4096;
        in = Wqkv; out = wqkv_t; K = 1024; N = 3072;
        n0 = (blk % 96) * 32; k0 = (blk / 96) * 32;
    } else {
        const int blk = bid - 7168;
        in = Wo; out = wo_t; K = 1024; N = 1024;
        n0 = (blk % 32) * 32; k0 = (blk / 32) * 32;
    }
    const int tx = tid & 31, ty = tid >> 5;  // (32,8)
    #pragma unroll
    for (int i = 0; i < 32; i += 8)
        tile[ty + i][tx] = in[(size_t)(k0 + ty + i) * N + n0 + tx];
    __syncthreads();
    #pragma unroll
    for (int i = 0; i < 32; i += 8)
        out[(size_t)(n0 + ty + i) * K + k0 + tx] = __float2bfloat16(tile[tx][ty + i]);
}

// ------- K3/K5: 128xBN BK=32 linear-LDS bf16 MFMA GEMM, B^T input ------------
// EPI==0: C fp32 = A@B^T + bias.  EPI==1: scatter qkv (bias added, bf16).
template <int EPI, int BN>
__global__ __launch_bounds__(256) void gemm_bt(
    const bf16* __restrict__ A,   // [M][K] bf16
    const bf16* __restrict__ Bt,  // [N][K] bf16
    const float* __restrict__ bias,  // [N] fp32
    float* __restrict__ Cf,          // EPI==0: [M][N] fp32
    bf16* __restrict__ qd, bf16* __restrict__ kd, bf16* __restrict__ vtd,
    int M, int N, int K) {
    constexpr int NFR = BN / 32;  // B frags per wave (wave n-span = BN/2)
    __shared__ bf16 As[128 * 32];
    __shared__ bf16 Bs[BN * 32];
    const int t = threadIdx.x;
    const int lane = t & 63;
    const int lr = lane & 15, lg = lane >> 4;
    const int wave = t >> 6;
    const int wr = wave >> 1, wc = wave & 1;  // 2x2 waves
    const int m0 = blockIdx.x * 128, n0 = blockIdx.y * BN;

    const bf16* aSrc = A + (size_t)(m0 + (t >> 2)) * K + (t & 3) * 8;
    const bf16* bSrc = Bt + (size_t)(n0 + (t >> 2)) * K + (t & 3) * 8;
    const size_t rowStep = (size_t)64 * K;

    f32x4 acc[4][NFR] = {};

    for (int k0 = 0; k0 < K; k0 += 32) {
        __syncthreads();
        async16(aSrc + k0, &As[t * 8]);
        async16(aSrc + rowStep + k0, &As[2048 + t * 8]);
        async16(bSrc + k0, &Bs[t * 8]);
        if constexpr (BN == 128) async16(bSrc + rowStep + k0, &Bs[2048 + t * 8]);
        __syncthreads();
        short8 af[4], bfr[NFR];
        #pragma unroll
        for (int i = 0; i < 4; ++i)
            af[i] = *reinterpret_cast<const short8*>(
                &As[(wr * 64 + i * 16 + lr) * 32 + lg * 8]);
        #pragma unroll
        for (int i = 0; i < NFR; ++i)
            bfr[i] = *reinterpret_cast<const short8*>(
                &Bs[(wc * (BN / 2) + i * 16 + lr) * 32 + lg * 8]);
        #pragma unroll
        for (int mi = 0; mi < 4; ++mi)
            #pragma unroll
            for (int ni = 0; ni < NFR; ++ni)
                acc[mi][ni] = __builtin_amdgcn_mfma_f32_16x16x32_bf16(
                    af[mi], bfr[ni], acc[mi][ni], 0, 0, 0);
    }

    #pragma unroll
    for (int mi = 0; mi < 4; ++mi) {
        #pragma unroll
        for (int ni = 0; ni < NFR; ++ni) {
            const int rowb = m0 + wr * 64 + mi * 16 + lg * 4;
            const int col = n0 + wc * (BN / 2) + ni * 16 + lr;
            if constexpr (EPI == 0) {
                #pragma unroll
                for (int r = 0; r < 4; ++r)
                    Cf[(size_t)(rowb + r) * N + col] = acc[mi][ni][r] + bias[col];
            } else {
                const float bs = bias[col];
                const int part = col >> 10;      // 0=q 1=k 2=v
                const int within = col & 1023;
                const int h = within >> 6, d = within & 63;
                const int b = rowb >> 11, s0 = rowb & 2047;
                const int bh = b * 16 + h;
                if (part == 2) {  // v^T: 4 consecutive s -> ushort4
                    ushort4 pk;
                    pk.x = f2b(acc[mi][ni][0] + bs);
                    pk.y = f2b(acc[mi][ni][1] + bs);
                    pk.z = f2b(acc[mi][ni][2] + bs);
                    pk.w = f2b(acc[mi][ni][3] + bs);
                    *reinterpret_cast<ushort4*>(
                        &vtd[((size_t)bh * 64 + d) * 2048 + s0]) = pk;
                } else {
                    bf16* dst = (part == 0) ? qd : kd;
                    #pragma unroll
                    for (int r = 0; r < 4; ++r)
                        dst[((size_t)bh * 2048 + s0 + r) * 64 + d] =
                            __float2bfloat16(acc[mi][ni][r] + bs);
                }
            }
        }
    }
}

// ---------------- K4: causal flash attention (round-6 version) ---------------
// grid 512 (1-D, XCD-pinned), block 256 = 4 waves = 2 units x 2 parities.
__global__ __launch_bounds__(256, 2) void attn_kernel(const bf16* __restrict__ q,
                                                      const bf16* __restrict__ k,
                                                      const bf16* __restrict__ vt,
                                                      bf16* __restrict__ o) {
    const int S = 2048;
    const int f = blockIdx.x;
    const int res = f & 7, m = f >> 3;
    const int grp = m >> 4;
    const int bh = res + 8 * grp;
    const int bxr = m & 15;
    const int bx = (grp & 2) ? (15 - bxr) : bxr;
    const int b = bh >> 4, h = bh & 15;
    const int w = threadIdx.x >> 6;
    const int u = w >> 1, par = w & 1;
    const int lane = threadIdx.x & 63;
    const int ln = lane & 31;
    const int hi = lane >> 5;
    const int P = 2 * (15 - bx) + u;     // 0..31
    const int qbaseA = P * 64;
    const int qbaseB = P * 64 + 32;

    const bf16* qp = q + (size_t)bh * S * 64;
    const bf16* kp = k + (size_t)bh * S * 64;
    const bf16* vp = vt + (size_t)bh * 64 * S;

    short8 qfA[4], qfB[4];
    #pragma unroll
    for (int i = 0; i < 4; ++i) {
        qfA[i] = *reinterpret_cast<const short8*>(
            &qp[(size_t)(qbaseA + ln) * 64 + i * 16 + hi * 8]);
        qfB[i] = *reinterpret_cast<const short8*>(
            &qp[(size_t)(qbaseB + ln) * 64 + i * 16 + hi * 8]);
    }

    f32x16 oA0 = {}, oA1 = {}, oB0 = {}, oB1 = {};
    f32x4 lsvA = {0.f, 0.f, 0.f, 0.f}, lsvB = {0.f, 0.f, 0.f, 0.f};

    short8 kA[4], kB[4], vA[4], vB[4];

    auto kload = [&](short8 (&kf)[4], int tile) {
        const bf16* base = &kp[(size_t)(tile * 32 + ln) * 64 + hi * 8];
        #pragma unroll
        for (int i = 0; i < 4; ++i)
            kf[i] = *reinterpret_cast<const short8*>(base + i * 16);
    };
    auto vload = [&](short8 (&vf)[4], int tile) {
        #pragma unroll
        for (int dblk = 0; dblk < 2; ++dblk)
            #pragma unroll
            for (int half = 0; half < 2; ++half)
                vf[dblk * 2 + half] = *reinterpret_cast<const short8*>(
                    &vp[(size_t)(dblk * 32 + ln) * S + tile * 32 + half * 16 +
                        hi * 8]);
    };

    auto body = [&](const short8 (&kf)[4], const short8 (&vf)[4],
                    const short8 (&qf)[4], f32x16& o0, f32x16& o1, f32x4& lsv,
                    bool diag) {
        f32x16 z0 = {}, z1 = {};
        z0 = __builtin_amdgcn_mfma_f32_32x32x16_bf16(kf[0], qf[0], z0, 0, 0, 0);
        z0 = __builtin_amdgcn_mfma_f32_32x32x16_bf16(kf[1], qf[1], z0, 0, 0, 0);
        z1 = __builtin_amdgcn_mfma_f32_32x32x16_bf16(kf[2], qf[2], z1, 0, 0, 0);
        z1 = __builtin_amdgcn_mfma_f32_32x32x16_bf16(kf[3], qf[3], z1, 0, 0, 0);
        const f32x16 z = z0 + z1;
        f32x16 pv;
        #pragma unroll
        for (int rr = 0; rr < 16; ++rr) {
            const int kreg = (rr & 3) + 8 * (rr >> 2) + 4 * hi;
            float e = __expf(z[rr] * 0.125f);
            if (diag && (kreg > ln)) e = 0.f;
            pv[rr] = e;
            lsv[rr & 3] += e;
        }
        unsigned a0, a1, b0, b1, c0, c1, d0, d1;
        asm("v_cvt_pk_bf16_f32 %0, %1, %2" : "=v"(a0) : "v"(pv[0]), "v"(pv[1]));
        asm("v_cvt_pk_bf16_f32 %0, %1, %2" : "=v"(a1) : "v"(pv[2]), "v"(pv[3]));
        asm("v_cvt_pk_bf16_f32 %0, %1, %2" : "=v"(b0) : "v"(pv[4]), "v"(pv[5]));
        asm("v_cvt_pk_bf16_f32 %0, %1, %2" : "=v"(b1) : "v"(pv[6]), "v"(pv[7]));
        asm("v_cvt_pk_bf16_f32 %0, %1, %2" : "=v"(c0) : "v"(pv[8]), "v"(pv[9]));
        asm("v_cvt_pk_bf16_f32 %0, %1, %2" : "=v"(c1) : "v"(pv[10]), "v"(pv[11]));
        asm("v_cvt_pk_bf16_f32 %0, %1, %2" : "=v"(d0) : "v"(pv[12]), "v"(pv[13]));
        asm("v_cvt_pk_bf16_f32 %0, %1, %2" : "=v"(d1) : "v"(pv[14]), "v"(pv[15]));
        asm("v_permlane32_swap_b32 %0, %1" : "+v"(a0), "+v"(b0));
        asm("v_permlane32_swap_b32 %0, %1" : "+v"(a1), "+v"(b1));
        asm("v_permlane32_swap_b32 %0, %1" : "+v"(c0), "+v"(d0));
        asm("v_permlane32_swap_b32 %0, %1" : "+v"(c1), "+v"(d1));
        u32x4 t0, t1;
        t0[0] = a0; t0[1] = a1; t0[2] = b0; t0[3] = b1;   // P[q][kv 0..15]
        t1[0] = c0; t1[1] = c1; t1[2] = d0; t1[3] = d1;   // P[q][kv 16..31]
        const short8 pa0 = __builtin_bit_cast(short8, t0);
        const short8 pa1 = __builtin_bit_cast(short8, t1);
        o0 = __builtin_amdgcn_mfma_f32_32x32x16_bf16(pa0, vf[0], o0, 0, 0, 0);
        o0 = __builtin_amdgcn_mfma_f32_32x32x16_bf16(pa1, vf[1], o0, 0, 0, 0);
        o1 = __builtin_amdgcn_mfma_f32_32x32x16_bf16(pa0, vf[2], o1, 0, 0, 0);
        o1 = __builtin_amdgcn_mfma_f32_32x32x16_bf16(pa1, vf[3], o1, 0, 0, 0);
    };

    auto dual = [&](const short8 (&kf)[4], const short8 (&vf)[4]) {
        body(kf, vf, qfA, oA0, oA1, lsvA, false);
        body(kf, vf, qfB, oB0, oB1, lsvB, false);
    };
    auto final_body = [&](const short8 (&kf)[4], const short8 (&vf)[4]) {
        if (par == 0) {
            body(kf, vf, qfA, oA0, oA1, lsvA, true);
            body(kf, vf, qfB, oB0, oB1, lsvB, false);
        } else {
            body(kf, vf, qfB, oB0, oB1, lsvB, true);
        }
    };

    kload(kA, par);
    vload(vA, par);
    int i = 0;
    for (; i + 2 <= P; i += 2) {
        kload(kB, par + 2 * (i + 1));
        vload(vB, par + 2 * (i + 1));
        dual(kA, vA);
        kload(kA, par + 2 * (i + 2));
        vload(vA, par + 2 * (i + 2));
        dual(kB, vB);
    }
    if (i < P) {
        kload(kB, par + 2 * P);
        vload(vB, par + 2 * P);
        dual(kA, vA);
        final_body(kB, vB);
    } else {
        final_body(kA, vA);
    }

    float lsA = (lsvA[0] + lsvA[1]) + (lsvA[2] + lsvA[3]);
    float lsB = (lsvB[0] + lsvB[1]) + (lsvB[2] + lsvB[3]);

    __shared__ float red[2][64][65];
    __shared__ float redl[2][64][2];
    if (par == 1) {
        float* dst = red[u][lane];
        #pragma unroll
        for (int rr = 0; rr < 16; ++rr) {
            dst[rr] = oA0[rr];
            dst[16 + rr] = oA1[rr];
            dst[32 + rr] = oB0[rr];
            dst[48 + rr] = oB1[rr];
        }
        redl[u][lane][0] = lsA;
        redl[u][lane][1] = lsB;
    }
    __syncthreads();
    if (par == 1) return;
    {
        const float* src = red[u][lane];
        #pragma unroll
        for (int rr = 0; rr < 16; ++rr) {
            oA0[rr] += src[rr];
            oA1[rr] += src[16 + rr];
            oB0[rr] += src[32 + rr];
            oB1[rr] += src[48 + rr];
        }
        lsA += redl[u][lane][0];
        lsB += redl[u][lane][1];
    }

    lsA += __shfl_xor(lsA, 32, 64);
    lsB += __shfl_xor(lsB, 32, 64);
    const float myInvA = 1.0f / lsA;
    const float myInvB = 1.0f / lsB;
    #pragma unroll
    for (int rr = 0; rr < 16; ++rr) {
        const int qrow = (rr & 3) + 8 * (rr >> 2) + 4 * hi;
        const float invA = __shfl(myInvA, qrow, 64);
        const float invB = __shfl(myInvB, qrow, 64);
        const size_t rowA = ((size_t)b * S + qbaseA + qrow) * 1024 + h * 64;
        const size_t rowB = ((size_t)b * S + qbaseB + qrow) * 1024 + h * 64;
        o[rowA + ln] = __float2bfloat16(oA0[rr] * invA);
        o[rowA + 32 + ln] = __float2bfloat16(oA1[rr] * invA);
        o[rowB + ln] = __float2bfloat16(oB0[rr] * invB);
        o[rowB + 32 + ln] = __float2bfloat16(oB1[rr] * invB);
    }
}

// -----------------------------------------------------------------------------
extern "C" void kernel_launch(void* const* d_in, const int* in_sizes, int n_in,
                              void* d_out, int out_size, void* d_ws, size_t ws_size,
                              hipStream_t stream) {
    const float* x = (const float*)d_in[0];     // [2,2048,1024]
    const float* Wqkv = (const float*)d_in[1];  // [1024,3072]
    const float* bqkv = (const float*)d_in[2];  // [3072]
    const float* Wo = (const float*)d_in[3];    // [1024,1024]
    const float* bo = (const float*)d_in[4];    // [1024]
    float* out = (float*)d_out;                 // [2,2048,1024] fp32
    char* ws = (char*)d_ws;

    // workspace layout (bytes), total 40 MB
    bf16* x_bf = (bf16*)(ws);                  //  8388608  [4096][1024]
    bf16* wqkv_t = (bf16*)(ws + 8388608);      //  6291456  [3072][1024]
    bf16* wo_t = (bf16*)(ws + 14680064);       //  2097152  [1024][1024]
    bf16* qb = (bf16*)(ws + 16777216);         //  8388608  [2,16,2048,64]
    bf16* kb = (bf16*)(ws + 25165824);         //  8388608  [2,16,2048,64]
    bf16* vtb = (bf16*)(ws + 33554432);        //  8388608  [2,16,64,2048]
    bf16* attn_o = x_bf;                       // alias: x_bf dead after gemm1

    prep_kernel<<<8192, 256, 0, stream>>>(x, x_bf, Wqkv, wqkv_t, Wo, wo_t);
    gemm_bt<1, 128><<<dim3(32, 24), 256, 0, stream>>>(
        x_bf, wqkv_t, bqkv, nullptr, qb, kb, vtb, 4096, 3072, 1024);
    attn_kernel<<<512, 256, 0, stream>>>(qb, kb, vtb, attn_o);
    gemm_bt<0, 64><<<dim3(32, 16), 256, 0, stream>>>(
        attn_o, wo_t, bo, out, nullptr, nullptr, nullptr, 4096, 1024, 1024);
}